// Round 5
// baseline (1521.185 us; speedup 1.0000x reference)
//
#include <hip/hip_runtime.h>

#define CHANNELS 32
#define HIDDEN 1024
#define LAYERS 8

typedef __attribute__((ext_vector_type(8))) short short8;
typedef __attribute__((ext_vector_type(4))) float float4v;
typedef __attribute__((ext_vector_type(2))) unsigned uint2v;

__device__ __forceinline__ short f2bf_rne(float f) {
    union { float f; unsigned u; } v; v.f = f;
    unsigned r = v.u + 0x7fffu + ((v.u >> 16) & 1u);
    return (short)(r >> 16);
}
__device__ __forceinline__ float bf2f(short h) {
    union { float f; unsigned u; } v; v.u = ((unsigned)(unsigned short)h) << 16;
    return v.f;
}
__device__ __forceinline__ float bfu2f(unsigned short h) {
    union { float f; unsigned u; } v; v.u = ((unsigned)h) << 16;
    return v.f;
}
// packed bf16 pair helpers: low half = channel 2k, high half = channel 2k+1
__device__ __forceinline__ float bflo(unsigned u) {
    union { float f; unsigned u; } v; v.u = u << 16; return v.f;
}
__device__ __forceinline__ float bfhi(unsigned u) {
    union { float f; unsigned u; } v; v.u = u & 0xffff0000u; return v.f;
}
__device__ __forceinline__ unsigned packbf(float x, float y) {
    return ((unsigned)(unsigned short)f2bf_rne(y) << 16) |
            (unsigned)(unsigned short)f2bf_rne(x);
}

// ------- fused pre-pass: degree+rank (one atomic pass) + feature init + counts --

__global__ __launch_bounds__(256)
void pre_kernel(const int* __restrict__ src, const int* __restrict__ tgt,
                int* __restrict__ deg2,
                int* __restrict__ rank1, int* __restrict__ rank2,
                const int* __restrict__ nodes, const float* __restrict__ emb,
                unsigned short* __restrict__ hi0, unsigned short* __restrict__ lo,
                const int* __restrict__ batch, float* __restrict__ counts,
                int n_nodes, int n_edges, int n_graphs,
                int degB, int initB) {
    int bid = blockIdx.x;
    int tid = threadIdx.x;
    if (bid < degB) {
        int base = bid * 2048;
#pragma unroll
        for (int j = 0; j < 8; j++) {
            int e = base + j * 256 + tid;
            if (e < n_edges) {
                int t = __builtin_nontemporal_load(tgt + e);
                int s = __builtin_nontemporal_load(src + e);
                int r1 = atomicAdd(&deg2[t], 1);
                int r2 = atomicAdd(&deg2[n_nodes + s], 1);
                __builtin_nontemporal_store(r1, rank1 + e);
                __builtin_nontemporal_store(r2, rank2 + e);
            }
        }
    } else if (bid < degB + initB) {
        // one thread per (node, 8-channel slab): float4 x2 emb read, short8 stores
        int gid = (bid - degB) * 256 + tid;
        int i = gid >> 2, c8 = (gid & 3) * 8;
        if (i < n_nodes) {
            const float* e = emb + nodes[i] * CHANNELS + c8;
            short8 hv, lv;
#pragma unroll
            for (int k = 0; k < 8; k++) {
                float v = e[k];
                short hsh = f2bf_rne(v);
                hv[k] = hsh;
                lv[k] = f2bf_rne(v - bf2f(hsh));
            }
            *(short8*)(hi0 + (size_t)i * CHANNELS + c8) = hv;
            *(short8*)(lo  + (size_t)i * CHANNELS + c8) = lv;
        }
    } else {
        int b = (bid - degB - initB) * 256 + tid;
        if (b < n_graphs) {
            int lo_i = 0, hi_i = n_nodes;
            while (lo_i < hi_i) { int mid = (lo_i + hi_i) >> 1; if (batch[mid] < b) lo_i = mid + 1; else hi_i = mid; }
            int s0 = lo_i;
            lo_i = 0; hi_i = n_nodes;
            while (lo_i < hi_i) { int mid = (lo_i + hi_i) >> 1; if (batch[mid] < b + 1) lo_i = mid + 1; else hi_i = mid; }
            counts[b] = (float)(lo_i - s0);
        }
    }
}

// ---------------- 3-kernel exclusive prefix scan over deg2[0..n2) ----------------

__global__ __launch_bounds__(256)
void scan_pass1(const int* __restrict__ deg, int* __restrict__ bs, int n) {
    __shared__ int sh[256];
    int t = threadIdx.x;
    int base = blockIdx.x * 2048 + t * 8;
    int s = 0;
#pragma unroll
    for (int j = 0; j < 8; j++) { int idx = base + j; if (idx < n) s += deg[idx]; }
    sh[t] = s; __syncthreads();
    for (int st = 128; st > 0; st >>= 1) { if (t < st) sh[t] += sh[t + st]; __syncthreads(); }
    if (t == 0) bs[blockIdx.x] = sh[0];
}

__global__ void scan_pass2(int* __restrict__ bs, int nb) {
    __shared__ int sh[1024];
    int t = threadIdx.x;
    int v = (t < nb) ? bs[t] : 0;
    sh[t] = v; __syncthreads();
    for (int off = 1; off < 1024; off <<= 1) {
        int u = (t >= off) ? sh[t - off] : 0; __syncthreads();
        sh[t] += u; __syncthreads();
    }
    if (t < nb) bs[t] = sh[t] - v;   // exclusive
}

__global__ __launch_bounds__(256)
void scan_pass3(const int* __restrict__ deg, const int* __restrict__ bs,
                int* __restrict__ off, int n) {
    __shared__ int sh[256];
    int t = threadIdx.x;
    int base = blockIdx.x * 2048 + t * 8;
    int v[8]; int s = 0;
#pragma unroll
    for (int j = 0; j < 8; j++) { int idx = base + j; v[j] = (idx < n) ? deg[idx] : 0; s += v[j]; }
    sh[t] = s; __syncthreads();
    for (int st = 1; st < 256; st <<= 1) {
        int u = (t >= st) ? sh[t - st] : 0; __syncthreads();
        sh[t] += u; __syncthreads();
    }
    int acc = bs[blockIdx.x] + sh[t] - s;
#pragma unroll
    for (int j = 0; j < 8; j++) {
        int idx = base + j;
        if (idx < n) off[idx] = acc;
        acc += v[j];
    }
}

// ---------------- placement: plain stores at off+rank, no atomics ----------------

__global__ __launch_bounds__(256)
void place_kernel(const int* __restrict__ src, const int* __restrict__ tgt,
                  const int* __restrict__ off2,
                  const int* __restrict__ rank1, const int* __restrict__ rank2,
                  int* __restrict__ nbr, int n_nodes, int n_edges) {
    int base = blockIdx.x * 2048;
#pragma unroll
    for (int j = 0; j < 8; j++) {
        int e = base + j * 256 + threadIdx.x;
        if (e < n_edges) {
            int t = __builtin_nontemporal_load(tgt + e);
            int s = __builtin_nontemporal_load(src + e);
            int r1 = __builtin_nontemporal_load(rank1 + e);
            int r2 = __builtin_nontemporal_load(rank2 + e);
            nbr[off2[t] + r1] = s;
            nbr[off2[n_nodes + s] + r2] = t;
        }
    }
}

// ---------------- fused layer: node-parallel pipelined gather + bf16 MFMA -----
// dwordx2 gathers: 8 lanes per node-row (8 B/lane), so each 16-lane TA cycle
// spans 2 cache lines (2x line-issue rate vs dword/16-lane format), and one
// load instruction covers 4 neighbor slots per direction. Lane map within a
// 32-lane group: q=c>>3 = slot offset, cl=c&7 = 4-channel quad. Slot partial
// sums fold with shfl_xor 8/16.

__global__ __launch_bounds__(256, 8)
void layer_mfma(const int* __restrict__ off2, const int* __restrict__ nbr,
                const float* __restrict__ wbase,
                const unsigned short* __restrict__ hi_in,
                unsigned short* __restrict__ hi_out,
                unsigned short* __restrict__ lo,
                int n_nodes, int n_edges) {
    __shared__ short A1h[64][32], A2h[64][32];
    __shared__ short W0h[32][32], W1h[32][32]; // [n][k]
    __shared__ int offIn[65], offOut[65];

    int tid = threadIdx.x;
    int nodeblock = blockIdx.x * 64;

    const uint2v* hid2 = (const uint2v*)hi_in;   // row stride 8 (64 B)
    const uint2v* lod2 = (const uint2v*)lo;

    // stage weights (transpose, bf16)
    for (int idx = tid; idx < CHANNELS * CHANNELS; idx += 256) {
        int k = idx >> 5, n = idx & 31;
        W0h[n][k] = f2bf_rne(wbase[idx]);
        W1h[n][k] = f2bf_rne(wbase[CHANNELS * CHANNELS + idx]);
    }
    // stage CSR offsets for this block's 64 nodes (both directions)
    if (tid < 65) {
        int idx = nodeblock + tid;
        offIn[tid]  = (idx <= n_nodes) ? off2[idx] : n_edges;
        int idx2 = n_nodes + idx;
        offOut[tid] = (idx2 < 2 * n_nodes) ? off2[idx2] : 2 * n_edges;
    }
    __syncthreads();

    int c = tid & 31, g = tid >> 5;
    int q  = c >> 3;          // slot offset 0..3
    int cl = c & 7;           // channel-quad: channels 4cl..4cl+3

    // ---- pipelined pass state (indices only) ----
    int d1_c, d2_c, bi_c, bo_c, nbl1_c, nbl2_c, node_c;
    {
        int local = g;
        node_c = nodeblock + local;
        bi_c = offIn[local];  d1_c = offIn[local + 1] - bi_c;
        bo_c = offOut[local]; d2_c = offOut[local + 1] - bo_c;
        nbl1_c = (c < d1_c) ? nbr[bi_c + c] : 0;
        nbl2_c = (c < d2_c) ? nbr[bo_c + c] : 0;
    }

    for (int pass = 0; pass < 8; pass++) {
        int i = node_c;
        int self = (i < n_nodes) ? i : 0;

        // self base row (hi+lo, 4 channels per lane) — issued first, used last
        float xb0 = 0.f, xb1 = 0.f, xb2 = 0.f, xb3 = 0.f;
        {
            unsigned bidx = (unsigned)(self * 8 + cl);
            uint2v H = hid2[bidx];
            uint2v L = lod2[bidx];
            if (i < n_nodes) {
                xb0 = bflo(H.x) + bflo(L.x);
                xb1 = bfhi(H.x) + bfhi(L.x);
                xb2 = bflo(H.y) + bflo(L.y);
                xb3 = bfhi(H.y) + bfhi(L.y);
            }
        }

        // prefetch next pass's index rows (lands during current gathers)
        int bi_n = 0, d1_n = 0, bo_n = 0, d2_n = 0, nbl1_n = 0, nbl2_n = 0, node_n = 0;
        if (pass < 7) {
            int local = (pass + 1) * 8 + g;
            node_n = nodeblock + local;
            bi_n = offIn[local];  d1_n = offIn[local + 1] - bi_n;
            bo_n = offOut[local]; d2_n = offOut[local + 1] - bo_n;
            nbl1_n = (c < d1_n) ? nbr[bi_n + c] : 0;
            nbl2_n = (c < d2_n) ? nbr[bo_n + c] : 0;
        }

        int local = pass * 8 + g;

        int m1 = d1_c < 32 ? d1_c : 32;
        int m2 = d2_c < 32 ? d2_c : 32;
        int mm = m1 > m2 ? m1 : m2;

        float sa0 = 0.f, sa1 = 0.f, sa2 = 0.f, sa3 = 0.f;
        float sb0 = 0.f, sb1 = 0.f, sb2 = 0.f, sb3 = 0.f;
        for (int j = 0; j < mm; j += 4) {
            int sl = j + q;
            int p = __shfl(nbl1_c, sl & 31, 32);
            int r = __shfl(nbl2_c, sl & 31, 32);
            bool v1 = sl < m1;
            bool v2 = sl < m2;
            p = v1 ? p : self;
            r = v2 ? r : self;
            uint2v U = hid2[(unsigned)(p * 8 + cl)];
            uint2v W = hid2[(unsigned)(r * 8 + cl)];
            sa0 += v1 ? bflo(U.x) : 0.f;
            sa1 += v1 ? bfhi(U.x) : 0.f;
            sa2 += v1 ? bflo(U.y) : 0.f;
            sa3 += v1 ? bfhi(U.y) : 0.f;
            sb0 += v2 ? bflo(W.x) : 0.f;
            sb1 += v2 ? bfhi(W.x) : 0.f;
            sb2 += v2 ? bflo(W.y) : 0.f;
            sb3 += v2 ? bfhi(W.y) : 0.f;
        }
        // fold slot partials across q (lanes c^8, c^16)
        sa0 += __shfl_xor(sa0, 8, 32);  sa0 += __shfl_xor(sa0, 16, 32);
        sa1 += __shfl_xor(sa1, 8, 32);  sa1 += __shfl_xor(sa1, 16, 32);
        sa2 += __shfl_xor(sa2, 8, 32);  sa2 += __shfl_xor(sa2, 16, 32);
        sa3 += __shfl_xor(sa3, 8, 32);  sa3 += __shfl_xor(sa3, 16, 32);
        sb0 += __shfl_xor(sb0, 8, 32);  sb0 += __shfl_xor(sb0, 16, 32);
        sb1 += __shfl_xor(sb1, 8, 32);  sb1 += __shfl_xor(sb1, 16, 32);
        sb2 += __shfl_xor(sb2, 8, 32);  sb2 += __shfl_xor(sb2, 16, 32);
        sb3 += __shfl_xor(sb3, 8, 32);  sb3 += __shfl_xor(sb3, 16, 32);

        // rare tails (degree > 32) — after fold, every lane adds full tail once
        for (int e = bi_c + 32; e < bi_c + d1_c; e++) {
            uint2v U = hid2[(unsigned)(nbr[e] * 8 + cl)];
            sa0 += bflo(U.x); sa1 += bfhi(U.x); sa2 += bflo(U.y); sa3 += bfhi(U.y);
        }
        for (int e = bo_c + 32; e < bo_c + d2_c; e++) {
            uint2v W = hid2[(unsigned)(nbr[e] * 8 + cl)];
            sb0 += bflo(W.x); sb1 += bfhi(W.x); sb2 += bflo(W.y); sb3 += bfhi(W.y);
        }

        unsigned pa0 = 0, pa1 = 0, pb0 = 0, pb1 = 0;
        if (i < n_nodes) {
            float n1 = 1.0f / (1.0f + (float)d1_c);
            float n2 = 1.0f / (1.0f + (float)d2_c);
            pa0 = packbf(n1 * (xb0 + sa0), n1 * (xb1 + sa1));
            pa1 = packbf(n1 * (xb2 + sa2), n1 * (xb3 + sa3));
            pb0 = packbf(n2 * (xb0 + sb0), n2 * (xb1 + sb1));
            pb1 = packbf(n2 * (xb2 + sb2), n2 * (xb3 + sb3));
        }
        // q=0 lanes store the A1 row (8 B each), q=1 lanes the A2 row
        if (q == 0) {
            uint2v st; st.x = pa0; st.y = pa1;
            *(uint2v*)&A1h[local][4 * cl] = st;
        } else if (q == 1) {
            uint2v st; st.x = pb0; st.y = pb1;
            *(uint2v*)&A2h[local][4 * cl] = st;
        }

        // rotate pipeline
        bi_c = bi_n; d1_c = d1_n; bo_c = bo_n; d2_c = d2_n;
        nbl1_c = nbl1_n; nbl2_c = nbl2_n; node_c = node_n;
    }
    __syncthreads();

    // ----- MFMA + epilogue -----
    int wv = tid >> 6, lane = tid & 63;
    int m = lane & 15, quad = lane >> 4;
    int row0 = wv * 16;

    short8 a1h = *(const short8*)&A1h[row0 + m][quad * 8];
    short8 a2h = *(const short8*)&A2h[row0 + m][quad * 8];

    float4v dd[4];
#pragma unroll
    for (int hh = 0; hh < 2; hh++) {
        int n0 = hh * 16 + m;
        short8 b0h = *(const short8*)&W0h[n0][quad * 8];
        short8 b1h = *(const short8*)&W1h[n0][quad * 8];
        float4v d1 = {0.f, 0.f, 0.f, 0.f};
        d1 = __builtin_amdgcn_mfma_f32_16x16x32_bf16(a1h, b0h, d1, 0, 0, 0);
        float4v d2 = {0.f, 0.f, 0.f, 0.f};
        d2 = __builtin_amdgcn_mfma_f32_16x16x32_bf16(a2h, b1h, d2, 0, 0, 0);
        dd[hh * 2] = d1; dd[hh * 2 + 1] = d2;
    }

#pragma unroll
    for (int hh = 0; hh < 2; hh++) {
        float4v d1 = dd[hh * 2], d2 = dd[hh * 2 + 1];
#pragma unroll
        for (int r = 0; r < 4; r++) {
            int local = row0 + quad * 4 + r;
            int node = nodeblock + local;
            if (node < n_nodes) {
                int col = hh * 16 + m;
                size_t idx = (size_t)node * CHANNELS + col;
                float base = bfu2f(hi_in[idx]) + bfu2f(lo[idx]);
                float v = base + fmaxf(d1[r], 0.f) + fmaxf(d2[r], 0.f);
                short hn = f2bf_rne(v);
                hi_out[idx] = (unsigned short)hn;
                lo[idx]     = (unsigned short)f2bf_rne(v - bf2f(hn));
            }
        }
    }
}

// ---------------- pooling: run-length accumulate over sorted batch ----------------

#define POOL_CHUNK 2048

__global__ __launch_bounds__(256)
void pool_kernel(const int* __restrict__ batch,
                 const unsigned short* __restrict__ hi,
                 const unsigned short* __restrict__ lo,
                 float* __restrict__ g, int n_nodes) {
    int c = threadIdx.x & 31;
    int r = threadIdx.x >> 5;
    int base = blockIdx.x * POOL_CHUNK;
    float acc = 0.f;
    int cur = -1;
    for (int it = 0; it < POOL_CHUNK / 8; it++) {
        int node = base + it * 8 + r;
        if (node >= n_nodes) break;
        int b = batch[node];
        if (b != cur) {
            if (cur >= 0) atomicAdd(&g[cur * CHANNELS + c], acc);
            acc = 0.f;
            cur = b;
        }
        size_t idx = (size_t)node * CHANNELS + c;
        acc += bfu2f(hi[idx]) + bfu2f(lo[idx]);
    }
    if (cur >= 0) atomicAdd(&g[cur * CHANNELS + c], acc);
}

// ---------------- MLP head: one block per graph ----------------

__global__ __launch_bounds__(256)
void mlp_kernel(const float* __restrict__ g, const float* __restrict__ counts,
                const float* __restrict__ hidden_w, const float* __restrict__ hidden_b,
                const float* __restrict__ out_w, float* __restrict__ out) {
    __shared__ float grow[CHANNELS];
    __shared__ float red[256];
    int graph = blockIdx.x;
    int tid = threadIdx.x;
    if (tid < CHANNELS) grow[tid] = g[graph * CHANNELS + tid] / counts[graph];
    __syncthreads();
    float partial = 0.f;
    for (int q = 0; q < HIDDEN / 256; q++) {
        int j = q * 256 + tid;
        float h = hidden_b[j];
#pragma unroll
        for (int k = 0; k < CHANNELS; k++) h += grow[k] * hidden_w[k * HIDDEN + j];
        partial += fmaxf(h, 0.f) * out_w[j];
    }
    red[tid] = partial;
    __syncthreads();
    for (int s = 128; s > 0; s >>= 1) {
        if (tid < s) red[tid] += red[tid + s];
        __syncthreads();
    }
    if (tid == 0) out[graph] = red[0];
}

// ---------------- launch ----------------

extern "C" void kernel_launch(void* const* d_in, const int* in_sizes, int n_in,
                              void* d_out, int out_size, void* d_ws, size_t ws_size,
                              hipStream_t stream) {
    const int*   nodes    = (const int*)d_in[0];
    const int*   sources  = (const int*)d_in[1];
    const int*   targets  = (const int*)d_in[2];
    const int*   batch    = (const int*)d_in[3];
    const float* emb      = (const float*)d_in[4];
    const float* conv_w   = (const float*)d_in[5];
    const float* hidden_w = (const float*)d_in[6];
    const float* hidden_b = (const float*)d_in[7];
    const float* out_w    = (const float*)d_in[8];
    float* out = (float*)d_out;

    const int n_nodes  = in_sizes[0];
    const int n_edges  = in_sizes[1];
    const int n_graphs = out_size;
    const int n2 = 2 * n_nodes;

    char* ws = (char*)d_ws;
    unsigned short* hi0 = (unsigned short*)ws; ws += (size_t)n_nodes * CHANNELS * 2;
    unsigned short* hi1 = (unsigned short*)ws; ws += (size_t)n_nodes * CHANNELS * 2;
    unsigned short* lo  = (unsigned short*)ws; ws += (size_t)n_nodes * CHANNELS * 2;
    int*   deg2   = (int*)ws;   ws += (size_t)n2 * 4;
    int*   off2   = (int*)ws;   ws += (size_t)n2 * 4;
    int*   rank1  = (int*)ws;   ws += (size_t)n_edges * 4;
    int*   rank2  = (int*)ws;   ws += (size_t)n_edges * 4;
    int*   nbr    = (int*)ws;   ws += (size_t)2 * n_edges * 4;
    int*   bsums  = (int*)ws;   ws += 4096;
    float* g      = (float*)ws; ws += (size_t)n_graphs * CHANNELS * 4;
    float* counts = (float*)ws; ws += (size_t)n_graphs * 4;

    hipMemsetAsync(deg2, 0, (size_t)n2 * 4, stream);
    hipMemsetAsync(g, 0, (size_t)n_graphs * CHANNELS * 4, stream);

    int echunks = (n_edges + 2047) / 2048;
    int degB  = echunks;                     // 1x edge coverage, ranked atomics
    int initB = (n_nodes * 4 + 255) / 256;   // 1 thread per 8 channels
    int cntB  = (n_graphs + 255) / 256;

    // 1. fused: degree+rank atomics + hi/lo init + graph counts
    pre_kernel<<<degB + initB + cntB, 256, 0, stream>>>(sources, targets, deg2,
                                                        rank1, rank2,
                                                        nodes, emb, hi0, lo,
                                                        batch, counts,
                                                        n_nodes, n_edges, n_graphs,
                                                        degB, initB);

    // 2. exclusive scan deg2 -> off2
    int nblk = (n2 + 2047) / 2048;
    scan_pass1<<<nblk, 256, 0, stream>>>(deg2, bsums, n2);
    scan_pass2<<<1, 1024, 0, stream>>>(bsums, nblk);
    scan_pass3<<<nblk, 256, 0, stream>>>(deg2, bsums, off2, n2);

    // 3. placement: plain stores at off+rank (no atomics)
    place_kernel<<<echunks, 256, 0, stream>>>(sources, targets, off2,
                                              rank1, rank2, nbr, n_nodes, n_edges);

    // 4. layers: hi plane ping-pongs, lo updated in place
    unsigned short* hin = hi0; unsigned short* hout = hi1;
    int lblocks = (n_nodes + 63) / 64;
    for (int l = 0; l < LAYERS; l++) {
        const float* wbase = conv_w + (size_t)l * 2 * CHANNELS * CHANNELS;
        layer_mfma<<<lblocks, 256, 0, stream>>>(off2, nbr, wbase,
                                                hin, hout, lo, n_nodes, n_edges);
        unsigned short* tmp = hin; hin = hout; hout = tmp;
    }
    // after 8 layers result is in hi0 (== hin) + lo

    // 5. pool + head
    int pool_blocks = (n_nodes + POOL_CHUNK - 1) / POOL_CHUNK;
    pool_kernel<<<pool_blocks, 256, 0, stream>>>(batch, hin, lo, g, n_nodes);
    mlp_kernel<<<n_graphs, 256, 0, stream>>>(g, counts, hidden_w, hidden_b, out_w, out);
}

// Round 6
// 1417.591 us; speedup vs baseline: 1.0731x; 1.0731x over previous
//
#include <hip/hip_runtime.h>

#define CHANNELS 32
#define HIDDEN 1024
#define LAYERS 8

typedef __attribute__((ext_vector_type(8))) short short8;
typedef __attribute__((ext_vector_type(4))) float float4v;

__device__ __forceinline__ short f2bf_rne(float f) {
    union { float f; unsigned u; } v; v.f = f;
    unsigned r = v.u + 0x7fffu + ((v.u >> 16) & 1u);
    return (short)(r >> 16);
}
__device__ __forceinline__ float bf2f(short h) {
    union { float f; unsigned u; } v; v.u = ((unsigned)(unsigned short)h) << 16;
    return v.f;
}
__device__ __forceinline__ float bfu2f(unsigned short h) {
    union { float f; unsigned u; } v; v.u = ((unsigned)h) << 16;
    return v.f;
}
// packed bf16 pair helpers: low half = channel 2cc, high half = channel 2cc+1
__device__ __forceinline__ float bflo(unsigned u) {
    union { float f; unsigned u; } v; v.u = u << 16; return v.f;
}
__device__ __forceinline__ float bfhi(unsigned u) {
    union { float f; unsigned u; } v; v.u = u & 0xffff0000u; return v.f;
}
__device__ __forceinline__ unsigned packbf(float x, float y) {
    return ((unsigned)(unsigned short)f2bf_rne(y) << 16) |
            (unsigned)(unsigned short)f2bf_rne(x);
}
// packed 16-bit degree counter access: counter i lives in degp[i>>1], half (i&1)
__device__ __forceinline__ int unpack16(unsigned pk, int half) {
    return (int)((pk >> (half * 16)) & 0xffffu);
}

// ------- fused pre-pass: packed degree+rank (one atomic pass) + feature init + counts --
// Each edge does two packed-16 atomicAdds; the returned old value IS the edge's
// rank within its node's neighbor list, so placement later needs no atomics.
// Both ranks packed into one dword store per edge.

__global__ __launch_bounds__(256)
void pre_kernel(const int* __restrict__ src, const int* __restrict__ tgt,
                unsigned* __restrict__ degp,
                unsigned* __restrict__ rankp,
                const int* __restrict__ nodes, const float* __restrict__ emb,
                unsigned short* __restrict__ hi0, unsigned short* __restrict__ lo,
                const int* __restrict__ batch, float* __restrict__ counts,
                int n_nodes, int n_edges, int n_graphs,
                int degB, int initB) {
    int bid = blockIdx.x;
    int tid = threadIdx.x;
    if (bid < degB) {
        int base = bid * 2048;
#pragma unroll
        for (int j = 0; j < 8; j++) {
            int e = base + j * 256 + tid;
            if (e < n_edges) {
                int t = __builtin_nontemporal_load(tgt + e);
                int s = __builtin_nontemporal_load(src + e);
                int si = n_nodes + s;
                unsigned o1 = atomicAdd(&degp[t >> 1],  1u << ((t  & 1) * 16));
                unsigned o2 = atomicAdd(&degp[si >> 1], 1u << ((si & 1) * 16));
                unsigned r1 = (o1 >> ((t  & 1) * 16)) & 0xffffu;
                unsigned r2 = (o2 >> ((si & 1) * 16)) & 0xffffu;
                __builtin_nontemporal_store((r2 << 16) | r1, rankp + e);
            }
        }
    } else if (bid < degB + initB) {
        // one thread per (node, 8-channel slab): float4 x2 emb read, short8 stores
        int gid = (bid - degB) * 256 + tid;
        int i = gid >> 2, c8 = (gid & 3) * 8;
        if (i < n_nodes) {
            const float* e = emb + nodes[i] * CHANNELS + c8;
            short8 hv, lv;
#pragma unroll
            for (int k = 0; k < 8; k++) {
                float v = e[k];
                short hsh = f2bf_rne(v);
                hv[k] = hsh;
                lv[k] = f2bf_rne(v - bf2f(hsh));
            }
            *(short8*)(hi0 + (size_t)i * CHANNELS + c8) = hv;
            *(short8*)(lo  + (size_t)i * CHANNELS + c8) = lv;
        }
    } else {
        int b = (bid - degB - initB) * 256 + tid;
        if (b < n_graphs) {
            int lo_i = 0, hi_i = n_nodes;
            while (lo_i < hi_i) { int mid = (lo_i + hi_i) >> 1; if (batch[mid] < b) lo_i = mid + 1; else hi_i = mid; }
            int s0 = lo_i;
            lo_i = 0; hi_i = n_nodes;
            while (lo_i < hi_i) { int mid = (lo_i + hi_i) >> 1; if (batch[mid] < b + 1) lo_i = mid + 1; else hi_i = mid; }
            counts[b] = (float)(lo_i - s0);
        }
    }
}

// ------------ 3-kernel exclusive prefix scan over packed deg[0..n) ------------
// n is even; each thread covers 8 consecutive counters = 4 packed dwords.

__global__ __launch_bounds__(256)
void scan_pass1(const unsigned* __restrict__ degp, int* __restrict__ bs, int n) {
    __shared__ int sh[256];
    int t = threadIdx.x;
    int base = blockIdx.x * 2048 + t * 8;
    int s = 0;
#pragma unroll
    for (int w = 0; w < 4; w++) {
        int idx = base + 2 * w;
        if (idx < n) {
            unsigned pk = degp[idx >> 1];
            s += unpack16(pk, 0);
            if (idx + 1 < n) s += unpack16(pk, 1);
        }
    }
    sh[t] = s; __syncthreads();
    for (int st = 128; st > 0; st >>= 1) { if (t < st) sh[t] += sh[t + st]; __syncthreads(); }
    if (t == 0) bs[blockIdx.x] = sh[0];
}

__global__ void scan_pass2(int* __restrict__ bs, int nb) {
    __shared__ int sh[1024];
    int t = threadIdx.x;
    int v = (t < nb) ? bs[t] : 0;
    sh[t] = v; __syncthreads();
    for (int off = 1; off < 1024; off <<= 1) {
        int u = (t >= off) ? sh[t - off] : 0; __syncthreads();
        sh[t] += u; __syncthreads();
    }
    if (t < nb) bs[t] = sh[t] - v;   // exclusive
}

__global__ __launch_bounds__(256)
void scan_pass3(const unsigned* __restrict__ degp, const int* __restrict__ bs,
                int* __restrict__ off, int n) {
    __shared__ int sh[256];
    int t = threadIdx.x;
    int base = blockIdx.x * 2048 + t * 8;
    int v[8]; int s = 0;
#pragma unroll
    for (int w = 0; w < 4; w++) {
        int idx = base + 2 * w;
        int lo16 = 0, hi16 = 0;
        if (idx < n) {
            unsigned pk = degp[idx >> 1];
            lo16 = unpack16(pk, 0);
            hi16 = (idx + 1 < n) ? unpack16(pk, 1) : 0;
        }
        v[2 * w] = lo16; v[2 * w + 1] = hi16;
        s += lo16 + hi16;
    }
    sh[t] = s; __syncthreads();
    for (int st = 1; st < 256; st <<= 1) {
        int u = (t >= st) ? sh[t - st] : 0; __syncthreads();
        sh[t] += u; __syncthreads();
    }
    int acc = bs[blockIdx.x] + sh[t] - s;
#pragma unroll
    for (int j = 0; j < 8; j++) {
        int idx = base + j;
        if (idx < n) off[idx] = acc;
        acc += v[j];
    }
}

// ---------------- placement: plain stores at off+rank, no atomics ----------------

__global__ __launch_bounds__(256)
void place_kernel(const int* __restrict__ src, const int* __restrict__ tgt,
                  const int* __restrict__ off2,
                  const unsigned* __restrict__ rankp,
                  int* __restrict__ nbr, int n_nodes, int n_edges) {
    int base = blockIdx.x * 2048;
#pragma unroll
    for (int j = 0; j < 8; j++) {
        int e = base + j * 256 + threadIdx.x;
        if (e < n_edges) {
            int t = __builtin_nontemporal_load(tgt + e);
            int s = __builtin_nontemporal_load(src + e);
            unsigned rp = __builtin_nontemporal_load(rankp + e);
            int r1 = (int)(rp & 0xffffu);
            int r2 = (int)(rp >> 16);
            nbr[off2[t] + r1] = s;
            nbr[off2[n_nodes + s] + r2] = t;
        }
    }
}

// ---------------- fused layer: node-parallel pipelined gather + bf16 MFMA -----
// (round-4 structure, best measured: 64-VGPR / 8 blocks per CU, dword parity
// gathers in a j+=4 loop, epilogue reloads base row from global)

__global__ __launch_bounds__(256, 8)
void layer_mfma(const int* __restrict__ off2, const int* __restrict__ nbr,
                const float* __restrict__ wbase,
                const unsigned short* __restrict__ hi_in,
                unsigned short* __restrict__ hi_out,
                unsigned short* __restrict__ lo,
                int n_nodes, int n_edges) {
    __shared__ short A1h[64][32], A2h[64][32];
    __shared__ short W0h[32][32], W1h[32][32]; // [n][k]
    __shared__ int offIn[65], offOut[65];

    int tid = threadIdx.x;
    int nodeblock = blockIdx.x * 64;

    // stage weights (transpose, bf16)
    for (int idx = tid; idx < CHANNELS * CHANNELS; idx += 256) {
        int k = idx >> 5, n = idx & 31;
        W0h[n][k] = f2bf_rne(wbase[idx]);
        W1h[n][k] = f2bf_rne(wbase[CHANNELS * CHANNELS + idx]);
    }
    // stage CSR offsets for this block's 64 nodes (both directions)
    if (tid < 65) {
        int idx = nodeblock + tid;
        offIn[tid]  = (idx <= n_nodes) ? off2[idx] : n_edges;
        int idx2 = n_nodes + idx;
        offOut[tid] = (idx2 < 2 * n_nodes) ? off2[idx2] : 2 * n_edges;
    }
    __syncthreads();

    int c = tid & 31, g = tid >> 5;
    int h = c >> 4;            // parity 0/1
    int cc = c & 15;           // channel-pair index -> channels 2cc, 2cc+1

    // ---- pipelined pass state ----
    int bi_c, d1_c, bo_c, d2_c, nbl1_c, nbl2_c, node_c;
    float xvx_c, xvy_c;
    {
        int local = g;
        node_c = nodeblock + local;
        bi_c = offIn[local];  d1_c = offIn[local + 1] - bi_c;
        bo_c = offOut[local]; d2_c = offOut[local + 1] - bo_c;
        nbl1_c = (c < d1_c) ? nbr[bi_c + c] : 0;
        nbl2_c = (c < d2_c) ? nbr[bo_c + c] : 0;
        xvx_c = 0.f; xvy_c = 0.f;
        if (node_c < n_nodes) {
            unsigned hp = *(const unsigned*)(hi_in + (size_t)node_c * CHANNELS + 2 * cc);
            unsigned lp = *(const unsigned*)(lo    + (size_t)node_c * CHANNELS + 2 * cc);
            xvx_c = bflo(hp) + bflo(lp);
            xvy_c = bfhi(hp) + bfhi(lp);
        }
    }

    for (int pass = 0; pass < 8; pass++) {
        // prefetch next pass's index rows + x row (lands during current gathers)
        int bi_n = 0, d1_n = 0, bo_n = 0, d2_n = 0, nbl1_n = 0, nbl2_n = 0, node_n = 0;
        float xvx_n = 0.f, xvy_n = 0.f;
        if (pass < 7) {
            int local = (pass + 1) * 8 + g;
            node_n = nodeblock + local;
            bi_n = offIn[local];  d1_n = offIn[local + 1] - bi_n;
            bo_n = offOut[local]; d2_n = offOut[local + 1] - bo_n;
            nbl1_n = (c < d1_n) ? nbr[bi_n + c] : 0;
            nbl2_n = (c < d2_n) ? nbr[bo_n + c] : 0;
            if (node_n < n_nodes) {
                unsigned hp = *(const unsigned*)(hi_in + (size_t)node_n * CHANNELS + 2 * cc);
                unsigned lp = *(const unsigned*)(lo    + (size_t)node_n * CHANNELS + 2 * cc);
                xvx_n = bflo(hp) + bflo(lp);
                xvy_n = bfhi(hp) + bfhi(lp);
            }
        }

        int local = pass * 8 + g;
        int i = node_c;
        int self = (i < n_nodes) ? i : 0;

        int m1 = d1_c < 32 ? d1_c : 32;
        int m2 = d2_c < 32 ? d2_c : 32;
        int mm = m1 > m2 ? m1 : m2;

        float s1x = 0.f, s1y = 0.f, s2x = 0.f, s2y = 0.f;
        for (int j = 0; j < mm; j += 4) {
            int sl0 = j + h;
            int sl1 = j + 2 + h;
            int p0 = __shfl(nbl1_c, sl0 & 31, 32);
            int p1 = __shfl(nbl1_c, sl1 & 31, 32);
            int q0 = __shfl(nbl2_c, sl0 & 31, 32);
            int q1 = __shfl(nbl2_c, sl1 & 31, 32);
            bool v10 = sl0 < m1, v11 = sl1 < m1;
            bool v20 = sl0 < m2, v21 = sl1 < m2;
            p0 = v10 ? p0 : self;
            p1 = v11 ? p1 : self;
            q0 = v20 ? q0 : self;
            q1 = v21 ? q1 : self;
            unsigned u0 = *(const unsigned*)(hi_in + (size_t)p0 * CHANNELS + 2 * cc);
            unsigned u1 = *(const unsigned*)(hi_in + (size_t)p1 * CHANNELS + 2 * cc);
            unsigned w0 = *(const unsigned*)(hi_in + (size_t)q0 * CHANNELS + 2 * cc);
            unsigned w1 = *(const unsigned*)(hi_in + (size_t)q1 * CHANNELS + 2 * cc);
            s1x += v10 ? bflo(u0) : 0.f;
            s1y += v10 ? bfhi(u0) : 0.f;
            s1x += v11 ? bflo(u1) : 0.f;
            s1y += v11 ? bfhi(u1) : 0.f;
            s2x += v20 ? bflo(w0) : 0.f;
            s2y += v20 ? bfhi(w0) : 0.f;
            s2x += v21 ? bflo(w1) : 0.f;
            s2y += v21 ? bfhi(w1) : 0.f;
        }
        // fold parity halves (lane c <-> c^16 within the 32-lane group)
        s1x += __shfl_xor(s1x, 16, 32);
        s1y += __shfl_xor(s1y, 16, 32);
        s2x += __shfl_xor(s2x, 16, 32);
        s2y += __shfl_xor(s2y, 16, 32);

        // rare tails (degree > 32) — after fold, every lane adds full tail once
        for (int e = bi_c + 32; e < bi_c + d1_c; e++) {
            unsigned u = *(const unsigned*)(hi_in + (size_t)nbr[e] * CHANNELS + 2 * cc);
            s1x += bflo(u); s1y += bfhi(u);
        }
        for (int e = bo_c + 32; e < bo_c + d2_c; e++) {
            unsigned u = *(const unsigned*)(hi_in + (size_t)nbr[e] * CHANNELS + 2 * cc);
            s2x += bflo(u); s2y += bfhi(u);
        }

        unsigned pk1 = 0, pk2 = 0;
        if (i < n_nodes) {
            float n1 = 1.0f / (1.0f + (float)d1_c);
            float n2 = 1.0f / (1.0f + (float)d2_c);
            pk1 = packbf(n1 * (xvx_c + s1x), n1 * (xvy_c + s1y));
            pk2 = packbf(n2 * (xvx_c + s2x), n2 * (xvy_c + s2y));
        }
        // h=0 lanes store the A1 pair, h=1 lanes the A2 pair (one dword each)
        unsigned* dst = (h == 0) ? (unsigned*)&A1h[local][2 * cc]
                                 : (unsigned*)&A2h[local][2 * cc];
        *dst = (h == 0) ? pk1 : pk2;

        // rotate pipeline
        bi_c = bi_n; d1_c = d1_n; bo_c = bo_n; d2_c = d2_n;
        nbl1_c = nbl1_n; nbl2_c = nbl2_n;
        xvx_c = xvx_n; xvy_c = xvy_n; node_c = node_n;
    }
    __syncthreads();

    // ----- MFMA + epilogue -----
    int wv = tid >> 6, lane = tid & 63;
    int m = lane & 15, quad = lane >> 4;
    int row0 = wv * 16;

    short8 a1h = *(const short8*)&A1h[row0 + m][quad * 8];
    short8 a2h = *(const short8*)&A2h[row0 + m][quad * 8];

    float4v dd[4];
#pragma unroll
    for (int hh = 0; hh < 2; hh++) {
        int n0 = hh * 16 + m;
        short8 b0h = *(const short8*)&W0h[n0][quad * 8];
        short8 b1h = *(const short8*)&W1h[n0][quad * 8];
        float4v d1 = {0.f, 0.f, 0.f, 0.f};
        d1 = __builtin_amdgcn_mfma_f32_16x16x32_bf16(a1h, b0h, d1, 0, 0, 0);
        float4v d2 = {0.f, 0.f, 0.f, 0.f};
        d2 = __builtin_amdgcn_mfma_f32_16x16x32_bf16(a2h, b1h, d2, 0, 0, 0);
        dd[hh * 2] = d1; dd[hh * 2 + 1] = d2;
    }

#pragma unroll
    for (int hh = 0; hh < 2; hh++) {
        float4v d1 = dd[hh * 2], d2 = dd[hh * 2 + 1];
#pragma unroll
        for (int r = 0; r < 4; r++) {
            int local = row0 + quad * 4 + r;
            int node = nodeblock + local;
            if (node < n_nodes) {
                int col = hh * 16 + m;
                size_t idx = (size_t)node * CHANNELS + col;
                float base = bfu2f(hi_in[idx]) + bfu2f(lo[idx]);
                float v = base + fmaxf(d1[r], 0.f) + fmaxf(d2[r], 0.f);
                short hn = f2bf_rne(v);
                hi_out[idx] = (unsigned short)hn;
                lo[idx]     = (unsigned short)f2bf_rne(v - bf2f(hn));
            }
        }
    }
}

// ---------------- pooling: run-length accumulate over sorted batch ----------------

#define POOL_CHUNK 2048

__global__ __launch_bounds__(256)
void pool_kernel(const int* __restrict__ batch,
                 const unsigned short* __restrict__ hi,
                 const unsigned short* __restrict__ lo,
                 float* __restrict__ g, int n_nodes) {
    int c = threadIdx.x & 31;
    int r = threadIdx.x >> 5;
    int base = blockIdx.x * POOL_CHUNK;
    float acc = 0.f;
    int cur = -1;
    for (int it = 0; it < POOL_CHUNK / 8; it++) {
        int node = base + it * 8 + r;
        if (node >= n_nodes) break;
        int b = batch[node];
        if (b != cur) {
            if (cur >= 0) atomicAdd(&g[cur * CHANNELS + c], acc);
            acc = 0.f;
            cur = b;
        }
        size_t idx = (size_t)node * CHANNELS + c;
        acc += bfu2f(hi[idx]) + bfu2f(lo[idx]);
    }
    if (cur >= 0) atomicAdd(&g[cur * CHANNELS + c], acc);
}

// ---------------- MLP head: one block per graph ----------------

__global__ __launch_bounds__(256)
void mlp_kernel(const float* __restrict__ g, const float* __restrict__ counts,
                const float* __restrict__ hidden_w, const float* __restrict__ hidden_b,
                const float* __restrict__ out_w, float* __restrict__ out) {
    __shared__ float grow[CHANNELS];
    __shared__ float red[256];
    int graph = blockIdx.x;
    int tid = threadIdx.x;
    if (tid < CHANNELS) grow[tid] = g[graph * CHANNELS + tid] / counts[graph];
    __syncthreads();
    float partial = 0.f;
    for (int q = 0; q < HIDDEN / 256; q++) {
        int j = q * 256 + tid;
        float h = hidden_b[j];
#pragma unroll
        for (int k = 0; k < CHANNELS; k++) h += grow[k] * hidden_w[k * HIDDEN + j];
        partial += fmaxf(h, 0.f) * out_w[j];
    }
    red[tid] = partial;
    __syncthreads();
    for (int s = 128; s > 0; s >>= 1) {
        if (tid < s) red[tid] += red[tid + s];
        __syncthreads();
    }
    if (tid == 0) out[graph] = red[0];
}

// ---------------- launch ----------------

extern "C" void kernel_launch(void* const* d_in, const int* in_sizes, int n_in,
                              void* d_out, int out_size, void* d_ws, size_t ws_size,
                              hipStream_t stream) {
    const int*   nodes    = (const int*)d_in[0];
    const int*   sources  = (const int*)d_in[1];
    const int*   targets  = (const int*)d_in[2];
    const int*   batch    = (const int*)d_in[3];
    const float* emb      = (const float*)d_in[4];
    const float* conv_w   = (const float*)d_in[5];
    const float* hidden_w = (const float*)d_in[6];
    const float* hidden_b = (const float*)d_in[7];
    const float* out_w    = (const float*)d_in[8];
    float* out = (float*)d_out;

    const int n_nodes  = in_sizes[0];
    const int n_edges  = in_sizes[1];
    const int n_graphs = out_size;
    const int n2 = 2 * n_nodes;

    char* ws = (char*)d_ws;
    unsigned short* hi0 = (unsigned short*)ws; ws += (size_t)n_nodes * CHANNELS * 2;
    unsigned short* hi1 = (unsigned short*)ws; ws += (size_t)n_nodes * CHANNELS * 2;
    unsigned short* lo  = (unsigned short*)ws; ws += (size_t)n_nodes * CHANNELS * 2;
    unsigned* degp  = (unsigned*)ws; ws += (size_t)(n2 / 2 + 1) * 4;
    int*   off2   = (int*)ws;   ws += (size_t)n2 * 4;
    unsigned* rankp = (unsigned*)ws; ws += (size_t)n_edges * 4;
    int*   nbr    = (int*)ws;   ws += (size_t)2 * n_edges * 4;
    int*   bsums  = (int*)ws;   ws += 4096;
    float* g      = (float*)ws; ws += (size_t)n_graphs * CHANNELS * 4;
    float* counts = (float*)ws; ws += (size_t)n_graphs * 4;

    hipMemsetAsync(degp, 0, (size_t)(n2 / 2 + 1) * 4, stream);
    hipMemsetAsync(g, 0, (size_t)n_graphs * CHANNELS * 4, stream);

    int echunks = (n_edges + 2047) / 2048;
    int degB  = echunks;                     // 1x edge coverage, packed ranked atomics
    int initB = (n_nodes * 4 + 255) / 256;   // 1 thread per 8 channels
    int cntB  = (n_graphs + 255) / 256;

    // 1. fused: packed degree+rank atomics + hi/lo init + graph counts
    pre_kernel<<<degB + initB + cntB, 256, 0, stream>>>(sources, targets, degp,
                                                        rankp,
                                                        nodes, emb, hi0, lo,
                                                        batch, counts,
                                                        n_nodes, n_edges, n_graphs,
                                                        degB, initB);

    // 2. exclusive scan packed deg -> off2
    int nblk = (n2 + 2047) / 2048;
    scan_pass1<<<nblk, 256, 0, stream>>>(degp, bsums, n2);
    scan_pass2<<<1, 1024, 0, stream>>>(bsums, nblk);
    scan_pass3<<<nblk, 256, 0, stream>>>(degp, bsums, off2, n2);

    // 3. placement: plain stores at off+rank (no atomics)
    place_kernel<<<echunks, 256, 0, stream>>>(sources, targets, off2,
                                              rankp, nbr, n_nodes, n_edges);

    // 4. layers: hi plane ping-pongs, lo updated in place
    unsigned short* hin = hi0; unsigned short* hout = hi1;
    int lblocks = (n_nodes + 63) / 64;
    for (int l = 0; l < LAYERS; l++) {
        const float* wbase = conv_w + (size_t)l * 2 * CHANNELS * CHANNELS;
        layer_mfma<<<lblocks, 256, 0, stream>>>(off2, nbr, wbase,
                                                hin, hout, lo, n_nodes, n_edges);
        unsigned short* tmp = hin; hin = hout; hout = tmp;
    }
    // after 8 layers result is in hi0 (== hin) + lo

    // 5. pool + head
    int pool_blocks = (n_nodes + POOL_CHUNK - 1) / POOL_CHUNK;
    pool_kernel<<<pool_blocks, 256, 0, stream>>>(batch, hin, lo, g, n_nodes);
    mlp_kernel<<<n_graphs, 256, 0, stream>>>(g, counts, hidden_w, hidden_b, out_w, out);
}